// Round 1
// baseline (74.780 us; speedup 1.0000x reference)
//
#include <hip/hip_runtime.h>
#include <math.h>

#define BB 512
#define DD 128
#define KK 8
#define BOUNDARY 4

// ---------------- workspace layout (bytes) ----------------
// partS : 0    .. 2048      (512 float)  per-block loss partial sum
// partC : 2048 .. 4096      (512 int)    per-block hinge count
// Dm    : 4096 .. 4096+1MB  (512*512 float, col-major: Dm[c*512+r] = d(r,c))
// Written unconditionally -> no memset needed. No device-scope atomics/fences
// (prior rounds: single-kernel finalize costs 40-60 us cross-XCD tail).
//
// Pipeline: dist (tiled LDS, 256 blocks) -> select (per-column, 1 wave)
//           -> fin. Replaces the 512-blocks-each-stream-all-of-x fused kernel:
//  * L2 read traffic 128 MB -> ~8 MB (each 32x32 tile reads only its 2 panels)
//  * top-k candidate array kept in VGPRs (predicated pop, no runtime index ->
//    no scratch; the old v[bi>>6] write demoted v[8] to local memory and put
//    8 scratch loads per extraction pass on the serial critical path)
//  * the <=16 positive distances are read from Dm instead of recomputed dots.
// Fallback: if ws_size can't hold Dm, run the proven fused path.

// ============================ kernel 1: distances ============================
__global__ __launch_bounds__(256) void dist_kernel(
    const float* __restrict__ x, float* __restrict__ Dm)
{
    __shared__ float4 As[32 * 33];     // stride 33 float4: breaks 32-way banks
    __shared__ float4 Bs[32 * 33];
    __shared__ float  sqA[32], sqB[32];

    const int t  = threadIdx.x;        // 0..255
    const int r0 = blockIdx.y * 32;    // row-tile base (r index of d)
    const int c0 = blockIdx.x * 32;    // col-tile base (column k of d)

    // stage both 32x128 panels (each contiguous 16 KB of x), coalesced
    const float4* xa = (const float4*)(x + r0 * DD);
    const float4* xb = (const float4*)(x + c0 * DD);
#pragma unroll
    for (int i = 0; i < 4; ++i) {
        int f = t + 256 * i;           // 0..1023 float4 of the panel
        int row = f >> 5, col = f & 31;
        As[row * 33 + col] = xa[f];
        Bs[row * 33 + col] = xb[f];
    }
    __syncthreads();

    // squared norms of the 64 staged rows (accumulation order matches the
    // main dot loop so the diagonal cancels to exactly 0)
    if (t < 64) {
        const float4* P = (t < 32) ? As : Bs;
        int row = t & 31;
        float s0 = 0.f, s1 = 0.f, s2 = 0.f, s3 = 0.f;
#pragma unroll 8
        for (int k = 0; k < 32; ++k) {
            float4 a = P[row * 33 + k];
            s0 += a.x * a.x; s1 += a.y * a.y; s2 += a.z * a.z; s3 += a.w * a.w;
        }
        float s = (s0 + s1) + (s2 + s3);
        if (t < 32) sqA[row] = s; else sqB[row] = s;
    }
    __syncthreads();

    const int cl = t & 31;             // column within tile (Bs row, broadcast-free A)
    const int rg = (t >> 5) * 4;       // row-group base: rows rg..rg+3
    float4 acc0 = {0,0,0,0}, acc1 = {0,0,0,0}, acc2 = {0,0,0,0}, acc3 = {0,0,0,0};
#pragma unroll 8
    for (int k = 0; k < 32; ++k) {
        float4 b  = Bs[cl * 33 + k];                 // 4-way bank conflict (ok)
        float4 a0 = As[(rg + 0) * 33 + k];           // same addr in 32-lane group
        float4 a1 = As[(rg + 1) * 33 + k];           //  -> LDS broadcast
        float4 a2 = As[(rg + 2) * 33 + k];
        float4 a3 = As[(rg + 3) * 33 + k];
        acc0.x += a0.x * b.x; acc0.y += a0.y * b.y; acc0.z += a0.z * b.z; acc0.w += a0.w * b.w;
        acc1.x += a1.x * b.x; acc1.y += a1.y * b.y; acc1.z += a1.z * b.z; acc1.w += a1.w * b.w;
        acc2.x += a2.x * b.x; acc2.y += a2.y * b.y; acc2.z += a2.z * b.z; acc2.w += a2.w * b.w;
        acc3.x += a3.x * b.x; acc3.y += a3.y * b.y; acc3.z += a3.z * b.z; acc3.w += a3.w * b.w;
    }
    float d0 = (acc0.x + acc0.y) + (acc0.z + acc0.w);
    float d1 = (acc1.x + acc1.y) + (acc1.z + acc1.w);
    float d2 = (acc2.x + acc2.y) + (acc2.z + acc2.w);
    float d3 = (acc3.x + acc3.y) + (acc3.z + acc3.w);
    float sb = sqB[cl];
    float q0 = fmaxf((sqA[rg + 0] + sb) - 2.f * d0, 0.f);
    float q1 = fmaxf((sqA[rg + 1] + sb) - 2.f * d1, 0.f);
    float q2 = fmaxf((sqA[rg + 2] + sb) - 2.f * d2, 0.f);
    float q3 = fmaxf((sqA[rg + 3] + sb) - 2.f * d3, 0.f);
    float4 o;
    o.x = (q0 == 0.f) ? 0.f : sqrtf(q0);
    o.y = (q1 == 0.f) ? 0.f : sqrtf(q1);
    o.z = (q2 == 0.f) ? 0.f : sqrtf(q2);
    o.w = (q3 == 0.f) ? 0.f : sqrtf(q3);
    *(float4*)(Dm + (c0 + cl) * BB + (r0 + rg)) = o;   // col-major, 16B-aligned
}

// ============================ kernel 2: selection ============================
__global__ __launch_bounds__(64) void select_kernel(
    const float* __restrict__ Dm, const int* __restrict__ tgt,
    float* __restrict__ partS, int* __restrict__ partC)
{
    __shared__ int   s_tgt[BB];
    __shared__ int   s_cnt[128];
    __shared__ int   s_sel[KK];
    __shared__ float s_selv[KK];
    __shared__ int   s_pr[16], s_pj[16];
    __shared__ float s_pv[16];
    __shared__ int   s_np;

    const int k = blockIdx.x;
    const int lane = threadIdx.x;      // 0..63, single wave

    s_cnt[lane] = 0; s_cnt[lane + 64] = 0;
    if (lane == 0) s_np = 0;
#pragma unroll
    for (int q = 0; q < 8; ++q) s_tgt[q * 64 + lane] = tgt[q * 64 + lane];
    __syncthreads();

    const int tk = s_tgt[k];
#pragma unroll
    for (int q = 0; q < 8; ++q) atomicAdd(&s_cnt[s_tgt[q * 64 + lane]], 1);

    // candidates: -d, same-class masked to -inf. Stays in VGPRs.
    const float* col = Dm + k * BB;
    float v[8];
#pragma unroll
    for (int q = 0; q < 8; ++q) {
        int r = q * 64 + lane;
        v[q] = (s_tgt[r] == tk) ? -INFINITY : -col[r];
    }

    // neg top-8 (lax.top_k set semantics: desc value, asc index on ties)
    for (int pass = 0; pass < KK; ++pass) {
        float bv = -INFINITY; int bq = -1;
#pragma unroll
        for (int q = 0; q < 8; ++q)
            if (v[q] > bv) { bv = v[q]; bq = q; }   // strict > keeps lowest q
        int bi = (bq >= 0) ? (bq * 64 + lane) : (1 << 30);
        for (int off = 32; off > 0; off >>= 1) {
            float ov = __shfl_down(bv, off);
            int   oi = __shfl_down(bi, off);
            if (ov > bv || (ov == bv && oi < bi)) { bv = ov; bi = oi; }
        }
        bv = __shfl(bv, 0); bi = __shfl(bi, 0);
        if (lane == 0) { s_sel[pass] = (bv == -INFINITY) ? -1 : bi; s_selv[pass] = bv; }
        // predicated pop: compile-time indices only -> no scratch spill
        const int  popq = bi >> 6;
        const bool mine = ((bi & 63) == lane);
#pragma unroll
        for (int q = 0; q < 8; ++q)
            if (mine && q == popq) v[q] = -INFINITY;
    }
    __syncthreads();

    // (anchor r, positive j) pairs: class size <= 3 -> <= 2 positives per sel
    for (int s = 0; s < KK; ++s) {
        int r = s_sel[s];
        if (r < 0) continue;
        int tr = s_tgt[r];
        if (s_cnt[tr] >= BOUNDARY) continue;
        float vn = s_selv[s];          // = -d[r,k]
#pragma unroll
        for (int q = 0; q < 8; ++q) {
            int j = q * 64 + lane;
            if (j != r && s_tgt[j] == tr) {
                int idx = atomicAdd(&s_np, 1);
                s_pr[idx] = r; s_pj[idx] = j; s_pv[idx] = vn;
            }
        }
    }
    __syncthreads();

    float s = 0.f; int c = 0;
    if (lane < s_np) {
        int r = s_pr[lane], j = s_pj[lane];
        float dpos = Dm[j * BB + r];   // d(r,j), read not recomputed
        float tv = dpos + s_pv[lane] + 1.0f;
        if (tv > 0.f) { s = tv; c = (tv > 1e-7f) ? 1 : 0; }
    }
    for (int off = 32; off > 0; off >>= 1) {
        s += __shfl_down(s, off);
        c += __shfl_down(c, off);
    }
    if (lane == 0) { partS[k] = s; partC[k] = c; }
}

// ==================== fallback: proven fused kernel =========================
__global__ __launch_bounds__(512, 4) void fused_kernel(
    const float* __restrict__ x, const int* __restrict__ tgt,
    float* __restrict__ partS, int* __restrict__ partC)
{
    __shared__ float4 xi4[DD / 4];
    __shared__ float s_vn[BB];
    __shared__ float s_sq[BB];
    __shared__ int   s_tgt[BB];
    __shared__ int   s_cnt[128];
    __shared__ int   s_sel[KK];
    __shared__ int   s_pr[16], s_pj[16];
    __shared__ int   s_np;

    int k = blockIdx.x;
    int t = threadIdx.x;
    if (t < DD / 4) xi4[t] = ((const float4*)(x + k * DD))[t];
    if (t < 128) s_cnt[t] = 0;
    if (t == 0) s_np = 0;
    s_tgt[t] = tgt[t];
    __syncthreads();
    int tk = s_tgt[k];

    float q0 = 0.f, q1 = 0.f, q2 = 0.f, q3 = 0.f;
    for (int c = 0; c < DD / 4; ++c) {
        float4 a = xi4[c];
        q0 += a.x * a.x; q1 += a.y * a.y; q2 += a.z * a.z; q3 += a.w * a.w;
    }
    float sqk = (q0 + q1) + (q2 + q3);

    {
        int g = t >> 3, sub = t & 7;
        for (int pass = 0; pass < 8; ++pass) {
            int r = pass * 64 + g;
            const float4* xr = (const float4*)(x + r * DD);
            float d0, d1, d2, d3, s0, s1, s2, s3;
            {
                float4 a = xi4[sub],      b = xr[sub];
                d0 = a.x*b.x + a.y*b.y + a.z*b.z + a.w*b.w;
                s0 = b.x*b.x + b.y*b.y + b.z*b.z + b.w*b.w;
            }
            {
                float4 a = xi4[sub + 8],  b = xr[sub + 8];
                d1 = a.x*b.x + a.y*b.y + a.z*b.z + a.w*b.w;
                s1 = b.x*b.x + b.y*b.y + b.z*b.z + b.w*b.w;
            }
            {
                float4 a = xi4[sub + 16], b = xr[sub + 16];
                d2 = a.x*b.x + a.y*b.y + a.z*b.z + a.w*b.w;
                s2 = b.x*b.x + b.y*b.y + b.z*b.z + b.w*b.w;
            }
            {
                float4 a = xi4[sub + 24], b = xr[sub + 24];
                d3 = a.x*b.x + a.y*b.y + a.z*b.z + a.w*b.w;
                s3 = b.x*b.x + b.y*b.y + b.z*b.z + b.w*b.w;
            }
            float dot = (d0 + d1) + (d2 + d3);
            float sq  = (s0 + s1) + (s2 + s3);
            for (int off = 4; off > 0; off >>= 1) {
                dot += __shfl_down(dot, off, 8);
                sq  += __shfl_down(sq,  off, 8);
            }
            if (sub == 0) {
                float dsq = fmaxf((sqk + sq) - 2.f * dot, 0.f);
                float dv = (dsq == 0.f) ? 0.f : sqrtf(dsq);
                s_sq[r] = sq;
                s_vn[r] = (s_tgt[r] == tk) ? -INFINITY : -dv;
            }
        }
    }
    __syncthreads();

    int wave = t >> 6, lane = t & 63;
    if (wave == 0) {
        float v[8];
        for (int q = 0; q < 8; ++q) v[q] = s_vn[q * 64 + lane];
        for (int pass = 0; pass < KK; ++pass) {
            float bv = -INFINITY; int bq = -1;
#pragma unroll
            for (int q = 0; q < 8; ++q)
                if (v[q] > bv) { bv = v[q]; bq = q; }
            int bi = (bq >= 0) ? (bq * 64 + lane) : (1 << 30);
            for (int off = 32; off > 0; off >>= 1) {
                float ov = __shfl_down(bv, off);
                int   oi = __shfl_down(bi, off);
                if (ov > bv || (ov == bv && oi < bi)) { bv = ov; bi = oi; }
            }
            bv = __shfl(bv, 0); bi = __shfl(bi, 0);
            if (lane == 0) s_sel[pass] = (bv == -INFINITY) ? -1 : bi;
            const int  popq = bi >> 6;
            const bool mine = ((bi & 63) == lane);
#pragma unroll
            for (int q = 0; q < 8; ++q)
                if (mine && q == popq) v[q] = -INFINITY;
        }
    } else if (wave == 1) {
        for (int q = 0; q < 8; ++q) atomicAdd(&s_cnt[s_tgt[q * 64 + lane]], 1);
    }
    __syncthreads();

    {
        int r = s_sel[wave];
        if (r >= 0) {
            int tr = s_tgt[r];
            if (s_cnt[tr] < BOUNDARY) {
                for (int j = lane; j < BB; j += 64)
                    if (j != r && s_tgt[j] == tr) {
                        int idx = atomicAdd(&s_np, 1);
                        s_pr[idx] = r; s_pj[idx] = j;
                    }
            }
        }
    }
    __syncthreads();

    float s = 0.f; int c = 0;
    if (t < s_np) {
        int r = s_pr[t], j = s_pj[t];
        const float4* xr = (const float4*)(x + r * DD);
        const float4* xj = (const float4*)(x + j * DD);
        float d0 = 0.f, d1 = 0.f, d2 = 0.f, d3 = 0.f;
        for (int cc = 0; cc < DD / 4; ++cc) {
            float4 a = xr[cc], b = xj[cc];
            d0 += a.x * b.x; d1 += a.y * b.y; d2 += a.z * b.z; d3 += a.w * b.w;
        }
        float dot = (d0 + d1) + (d2 + d3);
        float dsq = fmaxf((s_sq[r] + s_sq[j]) - 2.f * dot, 0.f);
        float dpos = (dsq == 0.f) ? 0.f : sqrtf(dsq);
        float tv = dpos + s_vn[r] + 1.0f;
        if (tv > 0.f) { s = tv; c = (tv > 1e-7f) ? 1 : 0; }
    }
    if (wave == 0) {
        for (int off = 32; off > 0; off >>= 1) {
            s += __shfl_down(s, off);
            c += __shfl_down(c, off);
        }
        if (lane == 0) { partS[k] = s; partC[k] = c; }
    }
}

// ============================ kernel 3: finalize =============================
__global__ __launch_bounds__(64) void fin_kernel(
    const float* __restrict__ partS, const int* __restrict__ partC,
    float* __restrict__ out)
{
    int lane = threadIdx.x;              // 512 partials = 128 x float4
    const float4* pS = (const float4*)partS;
    const int4*   pC = (const int4*)partC;
    float4 a = pS[lane], b = pS[lane + 64];
    int4   u = pC[lane], v = pC[lane + 64];
    float S = ((a.x + a.y) + (a.z + a.w)) + ((b.x + b.y) + (b.z + b.w));
    int   C = ((u.x + u.y) + (u.z + u.w)) + ((v.x + v.y) + (v.z + v.w));
    for (int off = 32; off > 0; off >>= 1) {
        S += __shfl_down(S, off);
        C += __shfl_down(C, off);
    }
    if (lane == 0) out[0] = S / ((float)C + 1e-7f);
}

extern "C" void kernel_launch(void* const* d_in, const int* in_sizes, int n_in,
                              void* d_out, int out_size, void* d_ws, size_t ws_size,
                              hipStream_t stream) {
    const float* x   = (const float*)d_in[0];
    const int*   tgt = (const int*)d_in[1];
    float* out = (float*)d_out;

    char* ws = (char*)d_ws;
    float* partS = (float*)(ws + 0);
    int*   partC = (int*)(ws + 2048);
    float* Dm    = (float*)(ws + 4096);

    if (ws_size >= 4096 + (size_t)BB * BB * sizeof(float)) {
        dist_kernel<<<dim3(16, 16), 256, 0, stream>>>(x, Dm);
        select_kernel<<<BB, 64, 0, stream>>>(Dm, tgt, partS, partC);
    } else {
        fused_kernel<<<BB, 512, 0, stream>>>(x, tgt, partS, partC);
    }
    fin_kernel<<<1, 64, 0, stream>>>(partS, partC, out);
}

// Round 2
// 71.495 us; speedup vs baseline: 1.0459x; 1.0459x over previous
//
#include <hip/hip_runtime.h>
#include <math.h>

#define BB 512
#define DD 128
#define KK 8
#define BOUNDARY 4

// ---------------- workspace layout (bytes) ----------------
// partS : 0    .. 2048   (512 float)  per-block loss partial sum
// partC : 2048 .. 4096   (512 int)    per-block hinge count
// Written unconditionally by every block -> no memset needed.
// NO device-scope atomics/fences anywhere (prior session rounds 8-10: any
// single-kernel finalize costs 40-60 us of cross-XCD coherence tail; tiny
// 2nd dispatch wins).
//
// Round-1 post-mortem: a 3-kernel split (tiled dist -> select -> fin) cut
// theoretical L2 traffic 16x but REGRESSED +2.8 us == one extra graph-node
// gap. The compute kernels are each only a few us against a ~64 us harness
// floor (256 MB workspace poison-fill at 40 us + reset dispatches), so the
// minimum 2-launch structure wins. This file: proven fused kernel + the
// predicated top-k pop (the round-0 binary had a runtime-indexed v[bi>>6]
// write -> v[8] demoted to scratch; 8 scratch-load scans per extraction
// pass sat on wave 0's serial critical path while 7 waves waited).
//
// Occupancy curve (measured, prior session): 4 waves/CU = 77.4us, 8 = 73.9,
// 16 = 71.1, 32 = 75.1 -> pin 16 waves/CU (512 thr, __launch_bounds__(512,4)).
//
// Algebraic facts exploited (boundary = int(512/128) = 4):
//  * anchor rows belong to classes with <= 3 members, so the positive top-8
//    selects ALL same-class rows: mask_ap[i][j] == anchors[i] & tgt[j]==tgt[i] & i!=j.
//  * block k owns column k: its neg top-8 rows r are exactly the (i=r, k)
//    entries of mask_an, and d[r,k] = -s_vn[r] (selected negs are always
//    different-class; s_vn holds -d).
//  * the diagonal is never consumed (neg-masked; positives exclude j==r).
//  * the <= 16 positive distances d[r,j] per block are recomputed directly
//    from x (one 128-dim dot each) — hinge values only, not selections.

__global__ __launch_bounds__(512, 4) void fused_kernel(
    const float* __restrict__ x, const int* __restrict__ tgt,
    float* __restrict__ partS, int* __restrict__ partC)
{
    __shared__ float4 xi4[DD / 4];
    __shared__ float s_vn[BB];         // -d, masked to -inf on same-class
    __shared__ float s_sq[BB];         // squared norms of all rows
    __shared__ int   s_tgt[BB];
    __shared__ int   s_cnt[128];       // class histogram
    __shared__ int   s_sel[KK];        // selected neg rows, -1 invalid
    __shared__ int   s_pr[16], s_pj[16];
    __shared__ int   s_np;

    int k = blockIdx.x;
    int t = threadIdx.x;               // 0..511
    if (t < DD / 4) xi4[t] = ((const float4*)(x + k * DD))[t];
    if (t < 128) s_cnt[t] = 0;
    if (t == 0) s_np = 0;
    s_tgt[t] = tgt[t];
    __syncthreads();
    int tk = s_tgt[k];

    float q0 = 0.f, q1 = 0.f, q2 = 0.f, q3 = 0.f;
    for (int c = 0; c < DD / 4; ++c) {
        float4 a = xi4[c];
        q0 += a.x * a.x; q1 += a.y * a.y; q2 += a.z * a.z; q3 += a.w * a.w;
    }
    float sqk = (q0 + q1) + (q2 + q3);

    // distance loop: 8 lanes cooperate per row (coalesced 128-B segments).
    // g = t>>3 (0..63 row-groups), sub = t&7; 8 passes x 64 groups = 512 rows.
    {
        int g = t >> 3, sub = t & 7;
        for (int pass = 0; pass < 8; ++pass) {
            int r = pass * 64 + g;
            const float4* xr = (const float4*)(x + r * DD);
            float d0, d1, d2, d3, s0, s1, s2, s3;
            {
                float4 a = xi4[sub],      b = xr[sub];
                d0 = a.x*b.x + a.y*b.y + a.z*b.z + a.w*b.w;
                s0 = b.x*b.x + b.y*b.y + b.z*b.z + b.w*b.w;
            }
            {
                float4 a = xi4[sub + 8],  b = xr[sub + 8];
                d1 = a.x*b.x + a.y*b.y + a.z*b.z + a.w*b.w;
                s1 = b.x*b.x + b.y*b.y + b.z*b.z + b.w*b.w;
            }
            {
                float4 a = xi4[sub + 16], b = xr[sub + 16];
                d2 = a.x*b.x + a.y*b.y + a.z*b.z + a.w*b.w;
                s2 = b.x*b.x + b.y*b.y + b.z*b.z + b.w*b.w;
            }
            {
                float4 a = xi4[sub + 24], b = xr[sub + 24];
                d3 = a.x*b.x + a.y*b.y + a.z*b.z + a.w*b.w;
                s3 = b.x*b.x + b.y*b.y + b.z*b.z + b.w*b.w;
            }
            float dot = (d0 + d1) + (d2 + d3);
            float sq  = (s0 + s1) + (s2 + s3);
            for (int off = 4; off > 0; off >>= 1) {
                dot += __shfl_down(dot, off, 8);
                sq  += __shfl_down(sq,  off, 8);
            }
            if (sub == 0) {
                float dsq = fmaxf((sqk + sq) - 2.f * dot, 0.f);
                float dv = (dsq == 0.f) ? 0.f : sqrtf(dsq);
                s_sq[r] = sq;
                s_vn[r] = (s_tgt[r] == tk) ? -INFINITY : -dv;
            }
        }
    }
    __syncthreads();

    int wave = t >> 6, lane = t & 63;
    if (wave == 0) {
        // neg top-8: largest -d among different-class rows (lax.top_k order:
        // descending value, lower index on tie). Candidates stay in VGPRs:
        // the pop below uses compile-time indices only (no scratch demotion).
        float v[8];
#pragma unroll
        for (int q = 0; q < 8; ++q) v[q] = s_vn[q * 64 + lane];
        for (int pass = 0; pass < KK; ++pass) {
            float bv = -INFINITY; int bq = -1;
#pragma unroll
            for (int q = 0; q < 8; ++q)
                if (v[q] > bv) { bv = v[q]; bq = q; }   // strict > keeps lowest q
            int bi = (bq >= 0) ? (bq * 64 + lane) : (1 << 30);
            for (int off = 32; off > 0; off >>= 1) {
                float ov = __shfl_down(bv, off);
                int   oi = __shfl_down(bi, off);
                if (ov > bv || (ov == bv && oi < bi)) { bv = ov; bi = oi; }
            }
            bv = __shfl(bv, 0); bi = __shfl(bi, 0);
            if (lane == 0) s_sel[pass] = (bv == -INFINITY) ? -1 : bi;
            const int  popq = bi >> 6;
            const bool mine = ((bi & 63) == lane);
#pragma unroll
            for (int q = 0; q < 8; ++q)
                if (mine && q == popq) v[q] = -INFINITY;
        }
    } else if (wave == 1) {
        // class histogram (includes self-counts)
#pragma unroll
        for (int q = 0; q < 8; ++q) atomicAdd(&s_cnt[s_tgt[q * 64 + lane]], 1);
    }
    __syncthreads();

    // collect (anchor r, positive j) pairs: 8 waves, one top-k slot each
    {
        int r = s_sel[wave];
        if (r >= 0) {
            int tr = s_tgt[r];
            if (s_cnt[tr] < BOUNDARY) {          // anchor: class size <= 3
                for (int j = lane; j < BB; j += 64)
                    if (j != r && s_tgt[j] == tr) {
                        int idx = atomicAdd(&s_np, 1);
                        s_pr[idx] = r; s_pj[idx] = j;
                    }
            }
        }
    }
    __syncthreads();

    // hinge terms: <= 16 pairs, all resident in wave 0
    float s = 0.f; int c = 0;
    if (t < s_np) {
        int r = s_pr[t], j = s_pj[t];
        const float4* xr = (const float4*)(x + r * DD);
        const float4* xj = (const float4*)(x + j * DD);
        float d0 = 0.f, d1 = 0.f, d2 = 0.f, d3 = 0.f;
        for (int cc = 0; cc < DD / 4; ++cc) {
            float4 a = xr[cc], b = xj[cc];
            d0 += a.x * b.x; d1 += a.y * b.y; d2 += a.z * b.z; d3 += a.w * b.w;
        }
        float dot = (d0 + d1) + (d2 + d3);
        float dsq = fmaxf((s_sq[r] + s_sq[j]) - 2.f * dot, 0.f);
        float dpos = (dsq == 0.f) ? 0.f : sqrtf(dsq);
        float tv = dpos + s_vn[r] + 1.0f;        // d[r,j] - d[r,k] + margin
        if (tv > 0.f) { s = tv; c = (tv > 1e-7f) ? 1 : 0; }
    }
    if (wave == 0) {
        for (int off = 32; off > 0; off >>= 1) {
            s += __shfl_down(s, off);
            c += __shfl_down(c, off);
        }
        if (lane == 0) { partS[k] = s; partC[k] = c; }
    }
}

__global__ __launch_bounds__(64) void fin_kernel(
    const float* __restrict__ partS, const int* __restrict__ partC,
    float* __restrict__ out)
{
    int lane = threadIdx.x;              // 0..63; 512 partials = 128 x float4
    const float4* pS = (const float4*)partS;
    const int4*   pC = (const int4*)partC;
    float4 a = pS[lane], b = pS[lane + 64];
    int4   u = pC[lane], v = pC[lane + 64];
    float S = ((a.x + a.y) + (a.z + a.w)) + ((b.x + b.y) + (b.z + b.w));
    int   C = ((u.x + u.y) + (u.z + u.w)) + ((v.x + v.y) + (v.z + v.w));
    for (int off = 32; off > 0; off >>= 1) {
        S += __shfl_down(S, off);
        C += __shfl_down(C, off);
    }
    if (lane == 0) out[0] = S / ((float)C + 1e-7f);
}

extern "C" void kernel_launch(void* const* d_in, const int* in_sizes, int n_in,
                              void* d_out, int out_size, void* d_ws, size_t ws_size,
                              hipStream_t stream) {
    const float* x   = (const float*)d_in[0];
    const int*   tgt = (const int*)d_in[1];
    float* out = (float*)d_out;

    char* ws = (char*)d_ws;
    float* partS = (float*)(ws + 0);
    int*   partC = (int*)(ws + 2048);

    fused_kernel<<<BB, 512, 0, stream>>>(x, tgt, partS, partC);
    fin_kernel<<<1, 64, 0, stream>>>(partS, partC, out);
}

// Round 3
// 71.030 us; speedup vs baseline: 1.0528x; 1.0066x over previous
//
#include <hip/hip_runtime.h>
#include <math.h>

#define BB 512
#define DD 128
#define KK 8
#define BOUNDARY 4

// ---------------- workspace layout (bytes) ----------------
// partS : 0    .. 2048   (512 float)  per-block loss partial sum
// partC : 2048 .. 4096   (512 int)    per-block hinge count
// Written unconditionally by every block -> no memset needed.
// NO device-scope atomics/fences anywhere (prior session: any single-kernel
// finalize costs 40-60 us of cross-XCD coherence tail; tiny 2nd dispatch wins).
//
// Round-1 post-mortem: 3-kernel split cut L2 traffic 16x but REGRESSED
// +2.8 us == one extra graph-node gap. Round-2: back to 2 launches = 71.5 us.
// Round-3 theory: fused is LATENCY-bound (per-CU L2 rate ~30 B/cyc, ~55% of
// ceiling; VALU floor ~2 us) -> distance loop restructured from 8 passes x
// 1 row/group to 4 passes x 2 rows/group: 8 global float4 loads in flight
// per lane (2x MLP), LDS a-loads shared across both rows, two independent
// shfl-reduce chains interleave their DS latencies. Per-row arithmetic and
// shuffle tree unchanged -> bitwise-identical distances (no top-k tie risk).
//
// Occupancy curve (measured, prior session): 4 waves/CU = 77.4us, 8 = 73.9,
// 16 = 71.1, 32 = 75.1 -> pin 16 waves/CU (512 thr, __launch_bounds__(512,4)).
//
// Algebraic facts exploited (boundary = int(512/128) = 4):
//  * anchor rows belong to classes with <= 3 members, so the positive top-8
//    selects ALL same-class rows: mask_ap[i][j] == anchors[i] & tgt[j]==tgt[i] & i!=j.
//  * block k owns column k: its neg top-8 rows r are exactly the (i=r, k)
//    entries of mask_an, and d[r,k] = -s_vn[r] (selected negs are always
//    different-class; s_vn holds -d).
//  * the diagonal is never consumed (neg-masked; positives exclude j==r).
//  * the <= 16 positive distances d[r,j] per block are recomputed directly
//    from x (one 128-dim dot each) — hinge values only, not selections.

__global__ __launch_bounds__(512, 4) void fused_kernel(
    const float* __restrict__ x, const int* __restrict__ tgt,
    float* __restrict__ partS, int* __restrict__ partC)
{
    __shared__ float4 xi4[DD / 4];
    __shared__ float s_vn[BB];         // -d, masked to -inf on same-class
    __shared__ float s_sq[BB];         // squared norms of all rows
    __shared__ int   s_tgt[BB];
    __shared__ int   s_cnt[128];       // class histogram
    __shared__ int   s_sel[KK];        // selected neg rows, -1 invalid
    __shared__ int   s_pr[16], s_pj[16];
    __shared__ int   s_np;

    int k = blockIdx.x;
    int t = threadIdx.x;               // 0..511
    if (t < DD / 4) xi4[t] = ((const float4*)(x + k * DD))[t];
    if (t < 128) s_cnt[t] = 0;
    if (t == 0) s_np = 0;
    s_tgt[t] = tgt[t];
    __syncthreads();
    int tk = s_tgt[k];

    float z0 = 0.f, z1 = 0.f, z2 = 0.f, z3 = 0.f;
    for (int c = 0; c < DD / 4; ++c) {
        float4 a = xi4[c];
        z0 += a.x * a.x; z1 += a.y * a.y; z2 += a.z * a.z; z3 += a.w * a.w;
    }
    float sqk = (z0 + z1) + (z2 + z3);

    // distance loop: 8 lanes cooperate per row (coalesced 128-B segments),
    // TWO rows per pass per group: g = t>>3 (0..63), sub = t&7; pass p covers
    // rows p*128+g and p*128+64+g. 8 global float4 loads in flight per lane;
    // a-loads (row-invariant) shared; two shfl chains interleave.
    {
        int g = t >> 3, sub = t & 7;
        for (int pass = 0; pass < 4; ++pass) {
            int r0 = pass * 128 + g;
            int r1 = r0 + 64;
            const float4* xr0 = (const float4*)(x + r0 * DD);
            const float4* xr1 = (const float4*)(x + r1 * DD);
            float4 a0 = xi4[sub], a1 = xi4[sub + 8], a2 = xi4[sub + 16], a3 = xi4[sub + 24];
            float4 p0 = xr0[sub], p1 = xr0[sub + 8], p2 = xr0[sub + 16], p3 = xr0[sub + 24];
            float4 q0 = xr1[sub], q1 = xr1[sub + 8], q2 = xr1[sub + 16], q3 = xr1[sub + 24];

            float dA0 = a0.x*p0.x + a0.y*p0.y + a0.z*p0.z + a0.w*p0.w;
            float sA0 = p0.x*p0.x + p0.y*p0.y + p0.z*p0.z + p0.w*p0.w;
            float dA1 = a1.x*p1.x + a1.y*p1.y + a1.z*p1.z + a1.w*p1.w;
            float sA1 = p1.x*p1.x + p1.y*p1.y + p1.z*p1.z + p1.w*p1.w;
            float dA2 = a2.x*p2.x + a2.y*p2.y + a2.z*p2.z + a2.w*p2.w;
            float sA2 = p2.x*p2.x + p2.y*p2.y + p2.z*p2.z + p2.w*p2.w;
            float dA3 = a3.x*p3.x + a3.y*p3.y + a3.z*p3.z + a3.w*p3.w;
            float sA3 = p3.x*p3.x + p3.y*p3.y + p3.z*p3.z + p3.w*p3.w;

            float dB0 = a0.x*q0.x + a0.y*q0.y + a0.z*q0.z + a0.w*q0.w;
            float sB0 = q0.x*q0.x + q0.y*q0.y + q0.z*q0.z + q0.w*q0.w;
            float dB1 = a1.x*q1.x + a1.y*q1.y + a1.z*q1.z + a1.w*q1.w;
            float sB1 = q1.x*q1.x + q1.y*q1.y + q1.z*q1.z + q1.w*q1.w;
            float dB2 = a2.x*q2.x + a2.y*q2.y + a2.z*q2.z + a2.w*q2.w;
            float sB2 = q2.x*q2.x + q2.y*q2.y + q2.z*q2.z + q2.w*q2.w;
            float dB3 = a3.x*q3.x + a3.y*q3.y + a3.z*q3.z + a3.w*q3.w;
            float sB3 = q3.x*q3.x + q3.y*q3.y + q3.z*q3.z + q3.w*q3.w;

            float dotA = (dA0 + dA1) + (dA2 + dA3);
            float sqA  = (sA0 + sA1) + (sA2 + sA3);
            float dotB = (dB0 + dB1) + (dB2 + dB3);
            float sqB  = (sB0 + sB1) + (sB2 + sB3);
            for (int off = 4; off > 0; off >>= 1) {
                dotA += __shfl_down(dotA, off, 8);
                sqA  += __shfl_down(sqA,  off, 8);
                dotB += __shfl_down(dotB, off, 8);
                sqB  += __shfl_down(sqB,  off, 8);
            }
            if (sub == 0) {
                float dsqA = fmaxf((sqk + sqA) - 2.f * dotA, 0.f);
                float dvA = (dsqA == 0.f) ? 0.f : sqrtf(dsqA);
                s_sq[r0] = sqA;
                s_vn[r0] = (s_tgt[r0] == tk) ? -INFINITY : -dvA;
                float dsqB = fmaxf((sqk + sqB) - 2.f * dotB, 0.f);
                float dvB = (dsqB == 0.f) ? 0.f : sqrtf(dsqB);
                s_sq[r1] = sqB;
                s_vn[r1] = (s_tgt[r1] == tk) ? -INFINITY : -dvB;
            }
        }
    }
    __syncthreads();

    int wave = t >> 6, lane = t & 63;
    if (wave == 0) {
        // neg top-8: largest -d among different-class rows (lax.top_k order:
        // descending value, lower index on tie). Candidates stay in VGPRs:
        // the pop below uses compile-time indices only (no scratch demotion).
        float v[8];
#pragma unroll
        for (int q = 0; q < 8; ++q) v[q] = s_vn[q * 64 + lane];
        for (int pass = 0; pass < KK; ++pass) {
            float bv = -INFINITY; int bq = -1;
#pragma unroll
            for (int q = 0; q < 8; ++q)
                if (v[q] > bv) { bv = v[q]; bq = q; }   // strict > keeps lowest q
            int bi = (bq >= 0) ? (bq * 64 + lane) : (1 << 30);
            for (int off = 32; off > 0; off >>= 1) {
                float ov = __shfl_down(bv, off);
                int   oi = __shfl_down(bi, off);
                if (ov > bv || (ov == bv && oi < bi)) { bv = ov; bi = oi; }
            }
            bv = __shfl(bv, 0); bi = __shfl(bi, 0);
            if (lane == 0) s_sel[pass] = (bv == -INFINITY) ? -1 : bi;
            const int  popq = bi >> 6;
            const bool mine = ((bi & 63) == lane);
#pragma unroll
            for (int q = 0; q < 8; ++q)
                if (mine && q == popq) v[q] = -INFINITY;
        }
    } else if (wave == 1) {
        // class histogram (includes self-counts)
#pragma unroll
        for (int q = 0; q < 8; ++q) atomicAdd(&s_cnt[s_tgt[q * 64 + lane]], 1);
    }
    __syncthreads();

    // collect (anchor r, positive j) pairs: 8 waves, one top-k slot each
    {
        int r = s_sel[wave];
        if (r >= 0) {
            int tr = s_tgt[r];
            if (s_cnt[tr] < BOUNDARY) {          // anchor: class size <= 3
                for (int j = lane; j < BB; j += 64)
                    if (j != r && s_tgt[j] == tr) {
                        int idx = atomicAdd(&s_np, 1);
                        s_pr[idx] = r; s_pj[idx] = j;
                    }
            }
        }
    }
    __syncthreads();

    // hinge terms: <= 16 pairs, all resident in wave 0
    float s = 0.f; int c = 0;
    if (t < s_np) {
        int r = s_pr[t], j = s_pj[t];
        const float4* xr = (const float4*)(x + r * DD);
        const float4* xj = (const float4*)(x + j * DD);
        float d0 = 0.f, d1 = 0.f, d2 = 0.f, d3 = 0.f;
        for (int cc = 0; cc < DD / 4; ++cc) {
            float4 a = xr[cc], b = xj[cc];
            d0 += a.x * b.x; d1 += a.y * b.y; d2 += a.z * b.z; d3 += a.w * b.w;
        }
        float dot = (d0 + d1) + (d2 + d3);
        float dsq = fmaxf((s_sq[r] + s_sq[j]) - 2.f * dot, 0.f);
        float dpos = (dsq == 0.f) ? 0.f : sqrtf(dsq);
        float tv = dpos + s_vn[r] + 1.0f;        // d[r,j] - d[r,k] + margin
        if (tv > 0.f) { s = tv; c = (tv > 1e-7f) ? 1 : 0; }
    }
    if (wave == 0) {
        for (int off = 32; off > 0; off >>= 1) {
            s += __shfl_down(s, off);
            c += __shfl_down(c, off);
        }
        if (lane == 0) { partS[k] = s; partC[k] = c; }
    }
}

__global__ __launch_bounds__(64) void fin_kernel(
    const float* __restrict__ partS, const int* __restrict__ partC,
    float* __restrict__ out)
{
    int lane = threadIdx.x;              // 0..63; 512 partials = 128 x float4
    const float4* pS = (const float4*)partS;
    const int4*   pC = (const int4*)partC;
    float4 a = pS[lane], b = pS[lane + 64];
    int4   u = pC[lane], v = pC[lane + 64];
    float S = ((a.x + a.y) + (a.z + a.w)) + ((b.x + b.y) + (b.z + b.w));
    int   C = ((u.x + u.y) + (u.z + u.w)) + ((v.x + v.y) + (v.z + v.w));
    for (int off = 32; off > 0; off >>= 1) {
        S += __shfl_down(S, off);
        C += __shfl_down(C, off);
    }
    if (lane == 0) out[0] = S / ((float)C + 1e-7f);
}

extern "C" void kernel_launch(void* const* d_in, const int* in_sizes, int n_in,
                              void* d_out, int out_size, void* d_ws, size_t ws_size,
                              hipStream_t stream) {
    const float* x   = (const float*)d_in[0];
    const int*   tgt = (const int*)d_in[1];
    float* out = (float*)d_out;

    char* ws = (char*)d_ws;
    float* partS = (float*)(ws + 0);
    int*   partC = (int*)(ws + 2048);

    fused_kernel<<<BB, 512, 0, stream>>>(x, tgt, partS, partC);
    fin_kernel<<<1, 64, 0, stream>>>(partS, partC, out);
}